// Round 1
// 269.313 us; speedup vs baseline: 1.0160x; 1.0160x over previous
//
#include <hip/hip_runtime.h>

// Match numpy rounding: no fma contraction anywhere in this file.
#pragma clang fp contract(off)

#define NCLS 22
#define WS_ 80
#define HS_ 60
#define P 4800          // 60*80
#define NBATCH 2
#define H 480
#define W 640
#define EPSF 1e-8f

#define JTILES 19       // ceil(P/256)
#define ICHUNKS 50
#define ILEN 96         // P / ICHUNKS

#define TSTRIDE 61      // table row stride (61 coprime w/ 32 banks -> <=2-way)
#define TSIZE (80 * TSTRIDE)

// Exact threshold midpoint: round-to-nearest-even(num/den) >= 0.9f
//   <=>  num/den >= M,  M = (pred(0.9f)+0.9f)/2 = 30198987 * 2^-25.
// M has 25 significant bits, den (f32) has 24 -> M*(double)den is EXACT in
// f64, so the comparison reproduces the IEEE f32 divide+compare bit-for-bit.
// (Tie q==M rounds to even significand 0x666666 == 0.9f, so ">=" inclusive.)
#define MID 0x1.CCCCCBp-1

// ---------------- kernel A: gather subsampled data + zero hough + table -------
// packed[t] = {u, v, nrm, bitcast(lab)};  pos[t] = {px, py};  z_s[t] = z
__global__ void prep_kernel(const int* __restrict__ label,
                            const float* __restrict__ vp,
                            float4* __restrict__ packed,
                            float2* __restrict__ pos,
                            float* __restrict__ z_s,
                            int4* __restrict__ hough4,
                            float* __restrict__ tab) {
    int t = blockIdx.x * blockDim.x + threadIdx.x;
    const int nthreads = gridDim.x * blockDim.x;

    // zero the hough accumulator (ws is poisoned 0xAA before every launch)
    const int HTOT4 = NBATCH * NCLS * P / 4;    // 52800 int4
    for (int q = t; q < HTOT4; q += nthreads) hough4[q] = make_int4(0, 0, 0, 0);

    // dist+EPS lookup table over integer displacement (|a|<=79, |b|<=59).
    // d2 = 64*(a*a+b*b) < 2^24 is an exact f32 integer, so this is the exact
    // reference chain: sqrtf(d2) correctly rounded, then +EPS rounded.
    for (int q = t; q < TSIZE; q += nthreads) {
        int a = q / TSTRIDE, b = q % TSTRIDE;
        float d2f = (float)(64 * (a * a + b * b));
        tab[q] = sqrtf(d2f) + EPSF;
    }

    if (t >= NBATCH * P) return;
    int n = t / P, p = t % P;
    int hs = p / WS_, ws = p % WS_;
    int y = hs * 8, x = ws * 8;
    int lab = label[((size_t)n * H + y) * W + x];
    const size_t HW = (size_t)H * W;
    size_t base = ((size_t)n * (3 * NCLS) + 3 * lab) * HW + (size_t)y * W + x;
    float u = vp[base];
    float v = vp[base + HW];
    float z = vp[base + 2 * HW];
    float nrm = sqrtf(u * u + v * v) + EPSF;    // exact, same as reference
    packed[t] = make_float4(u, v, nrm, __int_as_float(lab));
    pos[t] = make_float2((float)x, (float)y);   // exact small ints
    z_s[t] = z;
}

// ---------------- kernel A2: counting-sort voters by label --------------------
// sorted[slot] = {u, v, nrm, bitcast(lab<<16 | hs<<8 | ws)} grouped by label.
// Order within a class is nondeterministic (atomic cursors) — harmless: the
// only consumer sums integer votes, which is order-invariant. The original-
// order arrays (packed/pos/z_s) are untouched, so final_kernel's float sums
// keep their exact current bit patterns.
__global__ void __launch_bounds__(256) sort_kernel(
        const float4* __restrict__ packed,
        float4* __restrict__ sorted) {
    int n = blockIdx.x;
    int tid = threadIdx.x;
    __shared__ int cnt[NCLS];
    __shared__ int cur[NCLS];
    if (tid < NCLS) cnt[tid] = 0;
    __syncthreads();
    for (int p = tid; p < P; p += 256) {
        int lab = __float_as_int(packed[n * P + p].w);
        atomicAdd(&cnt[lab], 1);
    }
    __syncthreads();
    if (tid == 0) {
        int s = 0;
        for (int c = 0; c < NCLS; ++c) { cur[c] = s; s += cnt[c]; }
    }
    __syncthreads();
    for (int p = tid; p < P; p += 256) {
        float4 d = packed[n * P + p];
        int lab = __float_as_int(d.w);
        int slot = atomicAdd(&cur[lab], 1);
        int hs = p / WS_, ws = p % WS_;
        sorted[n * P + slot] =
            make_float4(d.x, d.y, d.z,
                        __int_as_float((lab << 16) | (hs << 8) | ws));
    }
}

// ---------------- kernel B: vote over label-sorted voters ---------------------
// grid (JTILES, ICHUNKS, NBATCH), block 256. Thread owns center j; loops over
// an i-chunk staged in LDS. Labels are piecewise-constant and wave-uniform, so
// the per-class count lives in one register and flushes with a rare uniform-
// branch atomic. No divide, no sqrt, no LDS histogram.
__global__ void __launch_bounds__(256) vote_kernel(
        const float4* __restrict__ sorted,
        const float* __restrict__ tab,
        int* __restrict__ hough) {
    __shared__ float4 sdat[ILEN];
    __shared__ float stab[TSIZE];
    int tid = threadIdx.x;
    int j = blockIdx.x * 256 + tid;           // may be >= P in last tile
    int n = blockIdx.z;
    int i0 = blockIdx.y * ILEN;

    for (int q = tid; q < TSIZE; q += 256) stab[q] = tab[q];
    if (tid < ILEN) sdat[tid] = sorted[n * P + i0 + tid];
    __syncthreads();

    bool jok = j < P;
    int jc = jok ? j : 0;
    int jx = jc % WS_;
    int jy = jc / WS_;
    int* hrow = &hough[(size_t)n * NCLS * P + jc];  // + c*P per class

    int acc = 0;
    int prevlab = -1;
    for (int ii = 0; ii < ILEN; ++ii) {
        float4 d = sdat[ii];
        int meta = __float_as_int(d.w);
        int lab = meta >> 16;
        if (lab != prevlab) {                 // uniform branch (sorted labels)
            if (prevlab > 0 && acc && jok) atomicAdd(hrow + prevlab * P, acc);
            acc = 0;
            prevlab = lab;
        }
        if (lab == 0) continue;               // uniform branch
        int ix = meta & 0xFF;
        int iy = (meta >> 8) & 0xFF;
        int ax = jx - ix;
        int ay = jy - iy;
        float t = stab[abs(ax) * TSTRIDE + abs(ay)];   // dist+EPS, exact
        float den = d.z * t;                  // nrm*(dist+EPS), exact ref chain
        float dxf = (float)(ax * 8);          // exact small ints
        float dyf = (float)(ay * 8);
        float num = d.x * dxf + d.y * dyf;    // mul,mul,add (contract off)
        // round(num/den) >= 0.9f  <=>  (double)num >= MID*(double)den (exact)
        int vote = ((double)num >= MID * (double)den) && ((ax | ay) != 0);
        acc += vote;
    }
    if (prevlab > 0 && acc && jok) atomicAdd(hrow + prevlab * P, acc);
}

// ---------------- kernel C: argmax + counts / inliers / z-mean / epilogue ------
__global__ void __launch_bounds__(256) final_kernel(
        const int* __restrict__ hough,
        const float4* __restrict__ packed,
        const float2* __restrict__ pos,
        const float* __restrict__ z_s,
        const float* __restrict__ extents,
        const float* __restrict__ meta,
        float* __restrict__ out) {
    int row_id = blockIdx.x;                  // n*NCLS + c
    int n = row_id / NCLS, c = row_id % NCLS;
    int tid = threadIdx.x;                    // 256

    // --- phase 1: argmax over j (first-max tie-break, matches jnp.argmax) ---
    const int* row = &hough[(size_t)row_id * P];
    int bi = tid;
    int bv = row[bi];
    for (int jj = tid + 256; jj < P; jj += 256) {
        int v = row[jj];
        if (v > bv) { bv = v; bi = jj; }      // keeps smallest index per stride
    }
    __shared__ int sv[256], si[256];
    sv[tid] = bv; si[tid] = bi;
    __syncthreads();
    for (int s = 128; s > 0; s >>= 1) {
        if (tid < s) {
            int v2 = sv[tid + s], i2 = si[tid + s];
            if (v2 > sv[tid] || (v2 == sv[tid] && i2 < si[tid])) {
                sv[tid] = v2; si[tid] = i2;
            }
        }
        __syncthreads();
    }
    int b = si[0];
    float mv = (float)sv[0];
    __syncthreads();

    // --- phase 2: counts, inliers at best, z sum ---
    float pxb = (float)((b % WS_) * 8);
    float pyb = (float)((b / WS_) * 8);
    int cnt = 0, nin = 0;
    float zs = 0.0f;
    for (int i = tid; i < P; i += 256) {
        float4 d = packed[n * P + i];
        int lab = __float_as_int(d.w);
        if (lab != c) continue;
        cnt++;
        if (c == 0) continue;                 // fg condition kills votes anyway
        float2 pp = pos[n * P + i];
        float dx = pxb - pp.x;
        float dy = pyb - pp.y;
        float d2 = dx * dx + dy * dy;
        float dist = sqrtf(d2);
        float num = d.x * dx + d.y * dy;
        float den = d.z * (dist + EPSF);
        float cosang = num / den;
        if ((cosang >= 0.9f) && (d2 > 0.0f)) {
            nin++;
            zs += z_s[n * P + i];
        }
    }
    __shared__ int sc[256], sn[256];
    __shared__ float sz[256];
    sc[tid] = cnt; sn[tid] = nin; sz[tid] = zs;
    __syncthreads();
    for (int s = 128; s > 0; s >>= 1) {
        if (tid < s) {
            sc[tid] += sc[tid + s];
            sn[tid] += sn[tid + s];
            sz[tid] += sz[tid + s];
        }
        __syncthreads();
    }
    if (tid == 0) {
        float cntf = (float)sc[0];
        float ninf = (float)sn[0];
        float z_mean = sz[0] / fmaxf(ninf, 1.0f);
        float zc = fmaxf(z_mean, 0.001f);
        bool valid = (cntf * 64.0f >= 500.0f) && (mv >= 10.0f)
                     && (mv >= 0.02f * cntf) && (c > 0);
        float vm = valid ? 1.0f : 0.0f;
        float fx  = meta[n * 9 + 0];
        float ppx = meta[n * 9 + 2];
        float fy  = meta[n * 9 + 4];
        float ppy = meta[n * 9 + 5];
        float ex = extents[c * 3 + 0];
        float ey = extents[c * 3 + 1];
        float bw = ex * fx / zc;
        float bh = ey * fy / zc;
        float cx = pxb, cy = pyb;
        float tx = (cx - ppx) * zc / fx;
        float ty = (cy - ppy) * zc / fy;
        float* box = out + (size_t)row_id * 7;
        box[0] = (float)n * vm;
        box[1] = (float)c * vm;
        box[2] = (cx - bw / 2.0f) * vm;
        box[3] = (cy - bh / 2.0f) * vm;
        box[4] = (cx + bw / 2.0f) * vm;
        box[5] = (cy + bh / 2.0f) * vm;
        box[6] = mv * vm;
        float* pose = out + (size_t)NBATCH * NCLS * 7 + (size_t)row_id * 7;
        pose[0] = vm;
        pose[1] = 0.0f;
        pose[2] = 0.0f;
        pose[3] = 0.0f;
        pose[4] = tx * vm;
        pose[5] = ty * vm;
        pose[6] = zc * vm;
    }
}

extern "C" void kernel_launch(void* const* d_in, const int* in_sizes, int n_in,
                              void* d_out, int out_size, void* d_ws, size_t ws_size,
                              hipStream_t stream) {
    const int*   label   = (const int*)d_in[0];     // (N,H,W) int32
    const float* vp      = (const float*)d_in[1];   // (N,66,H,W) f32
    const float* extents = (const float*)d_in[2];   // (22,3) f32
    // d_in[3] = poses (unused)
    const float* meta    = (const float*)d_in[4];   // (N,9) f32
    float* out = (float*)d_out;                     // 616 f32

    char* ws = (char*)d_ws;
    // layout (bytes): packed[9600]f4 (153600) | pos[9600]f2 (76800) |
    //   z_s[9600]f32 (38400) | hough[2*22*4800]i32 (844800) |
    //   sorted[9600]f4 (153600) | tab[4880]f32 (19520)
    float4* packed = (float4*)(ws + 0);
    float2* pos    = (float2*)(ws + 153600);
    float*  z_s    = (float*)(ws + 153600 + 76800);
    int*    hough  = (int*)(ws + 153600 + 76800 + 38400);
    float4* sorted = (float4*)(ws + 153600 + 76800 + 38400 + 844800);
    float*  tab    = (float*)(ws + 153600 + 76800 + 38400 + 844800 + 153600);

    prep_kernel<<<(NBATCH * P + 255) / 256, 256, 0, stream>>>(
        label, vp, packed, pos, z_s, (int4*)hough, tab);

    sort_kernel<<<NBATCH, 256, 0, stream>>>(packed, sorted);

    dim3 vgrid(JTILES, ICHUNKS, NBATCH);
    vote_kernel<<<vgrid, 256, 0, stream>>>(sorted, tab, hough);

    final_kernel<<<NBATCH * NCLS, 256, 0, stream>>>(hough, packed, pos, z_s,
                                                    extents, meta, out);
}

// Round 2
// 266.008 us; speedup vs baseline: 1.0286x; 1.0124x over previous
//
#include <hip/hip_runtime.h>

// Match numpy rounding: no fma contraction anywhere in this file.
#pragma clang fp contract(off)

#define NCLS 22
#define WS_ 80
#define HS_ 60
#define P 4800          // 60*80
#define NBATCH 2
#define H 480
#define W 640
#define EPSF 1e-8f

#define JTILES 19       // ceil(P/256)
#define ICHUNKS 50
#define ILEN 96         // P / ICHUNKS

#define TSTRIDE 61      // table row stride (61 coprime w/ 32 banks -> <=2-way)
#define TSIZE (80 * TSTRIDE)

// Exact threshold midpoint: round-to-nearest-even(num/den) >= 0.9f
//   <=>  num/den >= M,  M = (pred(0.9f)+0.9f)/2 = 30198987 * 2^-25.
// M has 25 significant bits, den (f32) has 24 -> M*(double)den is EXACT in
// f64, so the comparison reproduces the IEEE f32 divide+compare bit-for-bit.
// (Tie q==M rounds to even significand 0x666666 == 0.9f, so ">=" inclusive.)
#define MID 0x1.CCCCCBp-1

// ---------------- kernel A: gather subsampled data + zero hough + table -------
// packed[t] = {u, v, nrm, bitcast(lab)};  pos[t] = {px, py};  z_s[t] = z
__global__ void prep_kernel(const int* __restrict__ label,
                            const float* __restrict__ vp,
                            float4* __restrict__ packed,
                            float2* __restrict__ pos,
                            float* __restrict__ z_s,
                            int4* __restrict__ hough4,
                            float* __restrict__ tab) {
    int t = blockIdx.x * blockDim.x + threadIdx.x;
    const int nthreads = gridDim.x * blockDim.x;

    // zero the hough accumulator (ws is poisoned 0xAA before every launch)
    const int HTOT4 = NBATCH * NCLS * P / 4;    // 52800 int4
    for (int q = t; q < HTOT4; q += nthreads) hough4[q] = make_int4(0, 0, 0, 0);

    // dist+EPS lookup table over integer displacement (|a|<=79, |b|<=59).
    // d2 = 64*(a*a+b*b) < 2^24 is an exact f32 integer, so this is the exact
    // reference chain: sqrtf(d2) correctly rounded, then +EPS rounded.
    for (int q = t; q < TSIZE; q += nthreads) {
        int a = q / TSTRIDE, b = q % TSTRIDE;
        float d2f = (float)(64 * (a * a + b * b));
        tab[q] = sqrtf(d2f) + EPSF;
    }

    if (t >= NBATCH * P) return;
    int n = t / P, p = t % P;
    int hs = p / WS_, ws = p % WS_;
    int y = hs * 8, x = ws * 8;
    int lab = label[((size_t)n * H + y) * W + x];
    const size_t HW = (size_t)H * W;
    size_t base = ((size_t)n * (3 * NCLS) + 3 * lab) * HW + (size_t)y * W + x;
    float u = vp[base];
    float v = vp[base + HW];
    float z = vp[base + 2 * HW];
    float nrm = sqrtf(u * u + v * v) + EPSF;    // exact, same as reference
    packed[t] = make_float4(u, v, nrm, __int_as_float(lab));
    pos[t] = make_float2((float)x, (float)y);   // exact small ints
    z_s[t] = z;
}

// ---------------- kernel A2: counting-sort voters by label --------------------
// sorted[slot] = {8u, 8v, nrm, bitcast(lab<<16 | hs<<8 | ws)} grouped by label.
// 8u is an exact exponent shift, and fl((8u)*ax) == fl(u*(8ax)) (identical
// real products, correct rounding) -> vote math stays bit-exact while the
// inner loop drops the *8 on the displacement.
// Order within a class is nondeterministic (atomic cursors) — harmless: the
// only consumer sums integer votes, which is order-invariant. The original-
// order arrays (packed/pos/z_s) are untouched, so final_kernel's float sums
// keep their exact current bit patterns.
__global__ void __launch_bounds__(256) sort_kernel(
        const float4* __restrict__ packed,
        float4* __restrict__ sorted) {
    int n = blockIdx.x;
    int tid = threadIdx.x;
    __shared__ int cnt[NCLS];
    __shared__ int cur[NCLS];
    if (tid < NCLS) cnt[tid] = 0;
    __syncthreads();
    for (int p = tid; p < P; p += 256) {
        int lab = __float_as_int(packed[n * P + p].w);
        atomicAdd(&cnt[lab], 1);
    }
    __syncthreads();
    if (tid == 0) {
        int s = 0;
        for (int c = 0; c < NCLS; ++c) { cur[c] = s; s += cnt[c]; }
    }
    __syncthreads();
    for (int p = tid; p < P; p += 256) {
        float4 d = packed[n * P + p];
        int lab = __float_as_int(d.w);
        int slot = atomicAdd(&cur[lab], 1);
        int hs = p / WS_, ws = p % WS_;
        sorted[n * P + slot] =
            make_float4(d.x * 8.0f, d.y * 8.0f, d.z,
                        __int_as_float((lab << 16) | (hs << 8) | ws));
    }
}

// ---------------- kernel B: vote over label-sorted voters ---------------------
// grid (JTILES, ICHUNKS, NBATCH), block 256. Thread owns center j; loops over
// an i-chunk staged in LDS. Labels are piecewise-constant and wave-uniform, so
// the per-class count lives in one register and flushes with a rare uniform-
// branch atomic. No divide, no sqrt, no LDS histogram.
// Half-plane wave-skip: vote requires num >= MID*den > 0, so if no lane in
// the wave has num > 0 the whole tail (table read + f64 compare) is skipped
// via a uniform branch (~40% of iterations for random geometry).
__global__ void __launch_bounds__(256) vote_kernel(
        const float4* __restrict__ sorted,
        const float* __restrict__ tab,
        int* __restrict__ hough) {
    __shared__ float4 sdat[ILEN];
    __shared__ float stab[TSIZE];
    int tid = threadIdx.x;
    int j = blockIdx.x * 256 + tid;           // may be >= P in last tile
    int n = blockIdx.z;
    int i0 = blockIdx.y * ILEN;

    for (int q = tid; q < TSIZE; q += 256) stab[q] = tab[q];
    if (tid < ILEN) sdat[tid] = sorted[n * P + i0 + tid];
    __syncthreads();

    bool jok = j < P;
    int jc = jok ? j : 0;
    int jx = jc % WS_;
    int jy = jc / WS_;
    int* hrow = &hough[(size_t)n * NCLS * P + jc];  // + c*P per class

    int acc = 0;
    int prevlab = -1;
    for (int ii = 0; ii < ILEN; ++ii) {
        float4 d = sdat[ii];
        int meta = __float_as_int(d.w);
        int lab = meta >> 16;
        if (lab != prevlab) {                 // uniform branch (sorted labels)
            if (prevlab > 0 && acc && jok) atomicAdd(hrow + prevlab * P, acc);
            acc = 0;
            prevlab = lab;
        }
        if (lab == 0) continue;               // uniform branch
        int ix = meta & 0xFF;
        int iy = (meta >> 8) & 0xFF;
        int ax = jx - ix;
        int ay = jy - iy;
        float axf = (float)ax;                // exact small ints
        float ayf = (float)ay;
        float num = d.x * axf + d.y * ayf;    // == u*dx + v*dy bit-exact
        // num <= 0 can never vote (den > 0 always: nrm >= eps, t >= eps,
        // product >= 1e-16 >> FLT_MIN). ax==ay==0 gives num==0 -> false,
        // matching the reference's dist>0 gate.
        if (__any(num > 0.0f)) {
            float t = stab[abs(ax) * TSTRIDE + abs(ay)];   // dist+EPS, exact
            float den = d.z * t;              // nrm*(dist+EPS), exact ref chain
            // round(num/den) >= 0.9f <=> (double)num >= MID*(double)den
            acc += ((double)num >= MID * (double)den) ? 1 : 0;
        }
    }
    if (prevlab > 0 && acc && jok) atomicAdd(hrow + prevlab * P, acc);
}

// ---------------- kernel C: argmax + counts / inliers / z-mean / epilogue ------
__global__ void __launch_bounds__(256) final_kernel(
        const int* __restrict__ hough,
        const float4* __restrict__ packed,
        const float2* __restrict__ pos,
        const float* __restrict__ z_s,
        const float* __restrict__ extents,
        const float* __restrict__ meta,
        float* __restrict__ out) {
    int row_id = blockIdx.x;                  // n*NCLS + c
    int n = row_id / NCLS, c = row_id % NCLS;
    int tid = threadIdx.x;                    // 256

    // --- phase 1: argmax over j (first-max tie-break, matches jnp.argmax) ---
    const int* row = &hough[(size_t)row_id * P];
    int bi = tid;
    int bv = row[bi];
    for (int jj = tid + 256; jj < P; jj += 256) {
        int v = row[jj];
        if (v > bv) { bv = v; bi = jj; }      // keeps smallest index per stride
    }
    __shared__ int sv[256], si[256];
    sv[tid] = bv; si[tid] = bi;
    __syncthreads();
    for (int s = 128; s > 0; s >>= 1) {
        if (tid < s) {
            int v2 = sv[tid + s], i2 = si[tid + s];
            if (v2 > sv[tid] || (v2 == sv[tid] && i2 < si[tid])) {
                sv[tid] = v2; si[tid] = i2;
            }
        }
        __syncthreads();
    }
    int b = si[0];
    float mv = (float)sv[0];
    __syncthreads();

    // --- phase 2: counts, inliers at best, z sum ---
    float pxb = (float)((b % WS_) * 8);
    float pyb = (float)((b / WS_) * 8);
    int cnt = 0, nin = 0;
    float zs = 0.0f;
    for (int i = tid; i < P; i += 256) {
        float4 d = packed[n * P + i];
        int lab = __float_as_int(d.w);
        if (lab != c) continue;
        cnt++;
        if (c == 0) continue;                 // fg condition kills votes anyway
        float2 pp = pos[n * P + i];
        float dx = pxb - pp.x;
        float dy = pyb - pp.y;
        float d2 = dx * dx + dy * dy;
        float dist = sqrtf(d2);
        float num = d.x * dx + d.y * dy;
        float den = d.z * (dist + EPSF);
        float cosang = num / den;
        if ((cosang >= 0.9f) && (d2 > 0.0f)) {
            nin++;
            zs += z_s[n * P + i];
        }
    }
    __shared__ int sc[256], sn[256];
    __shared__ float sz[256];
    sc[tid] = cnt; sn[tid] = nin; sz[tid] = zs;
    __syncthreads();
    for (int s = 128; s > 0; s >>= 1) {
        if (tid < s) {
            sc[tid] += sc[tid + s];
            sn[tid] += sn[tid + s];
            sz[tid] += sz[tid + s];
        }
        __syncthreads();
    }
    if (tid == 0) {
        float cntf = (float)sc[0];
        float ninf = (float)sn[0];
        float z_mean = sz[0] / fmaxf(ninf, 1.0f);
        float zc = fmaxf(z_mean, 0.001f);
        bool valid = (cntf * 64.0f >= 500.0f) && (mv >= 10.0f)
                     && (mv >= 0.02f * cntf) && (c > 0);
        float vm = valid ? 1.0f : 0.0f;
        float fx  = meta[n * 9 + 0];
        float ppx = meta[n * 9 + 2];
        float fy  = meta[n * 9 + 4];
        float ppy = meta[n * 9 + 5];
        float ex = extents[c * 3 + 0];
        float ey = extents[c * 3 + 1];
        float bw = ex * fx / zc;
        float bh = ey * fy / zc;
        float cx = pxb, cy = pyb;
        float tx = (cx - ppx) * zc / fx;
        float ty = (cy - ppy) * zc / fy;
        float* box = out + (size_t)row_id * 7;
        box[0] = (float)n * vm;
        box[1] = (float)c * vm;
        box[2] = (cx - bw / 2.0f) * vm;
        box[3] = (cy - bh / 2.0f) * vm;
        box[4] = (cx + bw / 2.0f) * vm;
        box[5] = (cy + bh / 2.0f) * vm;
        box[6] = mv * vm;
        float* pose = out + (size_t)NBATCH * NCLS * 7 + (size_t)row_id * 7;
        pose[0] = vm;
        pose[1] = 0.0f;
        pose[2] = 0.0f;
        pose[3] = 0.0f;
        pose[4] = tx * vm;
        pose[5] = ty * vm;
        pose[6] = zc * vm;
    }
}

extern "C" void kernel_launch(void* const* d_in, const int* in_sizes, int n_in,
                              void* d_out, int out_size, void* d_ws, size_t ws_size,
                              hipStream_t stream) {
    const int*   label   = (const int*)d_in[0];     // (N,H,W) int32
    const float* vp      = (const float*)d_in[1];   // (N,66,H,W) f32
    const float* extents = (const float*)d_in[2];   // (22,3) f32
    // d_in[3] = poses (unused)
    const float* meta    = (const float*)d_in[4];   // (N,9) f32
    float* out = (float*)d_out;                     // 616 f32

    char* ws = (char*)d_ws;
    // layout (bytes): packed[9600]f4 (153600) | pos[9600]f2 (76800) |
    //   z_s[9600]f32 (38400) | hough[2*22*4800]i32 (844800) |
    //   sorted[9600]f4 (153600) | tab[4880]f32 (19520)
    float4* packed = (float4*)(ws + 0);
    float2* pos    = (float2*)(ws + 153600);
    float*  z_s    = (float*)(ws + 153600 + 76800);
    int*    hough  = (int*)(ws + 153600 + 76800 + 38400);
    float4* sorted = (float4*)(ws + 153600 + 76800 + 38400 + 844800);
    float*  tab    = (float*)(ws + 153600 + 76800 + 38400 + 844800 + 153600);

    prep_kernel<<<(NBATCH * P + 255) / 256, 256, 0, stream>>>(
        label, vp, packed, pos, z_s, (int4*)hough, tab);

    sort_kernel<<<NBATCH, 256, 0, stream>>>(packed, sorted);

    dim3 vgrid(JTILES, ICHUNKS, NBATCH);
    vote_kernel<<<vgrid, 256, 0, stream>>>(sorted, tab, hough);

    final_kernel<<<NBATCH * NCLS, 256, 0, stream>>>(hough, packed, pos, z_s,
                                                    extents, meta, out);
}

// Round 3
// 264.701 us; speedup vs baseline: 1.0337x; 1.0049x over previous
//
#include <hip/hip_runtime.h>

// Match numpy rounding: no fma contraction anywhere in this file.
#pragma clang fp contract(off)

#define NCLS 22
#define WS_ 80
#define HS_ 60
#define P 4800          // 60*80
#define NBATCH 2
#define H 480
#define W 640
#define EPSF 1e-8f

#define JTILES 19       // ceil(P/256)
#define ICHUNKS 25
#define ILEN 192        // P / ICHUNKS

#define TSTRIDE 61      // table row stride (61 coprime w/ 32 banks -> <=2-way)
#define TSIZE (80 * TSTRIDE)

// Exact threshold midpoint: round-to-nearest-even(num/den) >= 0.9f
//   <=>  num/den >= M,  M = (pred(0.9f)+0.9f)/2 = 30198987 * 2^-25.
// M has 25 significant bits, den (f32) has 24 -> M*(double)den is EXACT in
// f64, so the comparison reproduces the IEEE f32 divide+compare bit-for-bit.
// (Tie q==M rounds to even significand 0x666666 == 0.9f, so ">=" inclusive.)
#define MID 0x1.CCCCCBp-1

// ---------------- kernel A: gather subsampled data + zero hough + table -------
// packed[t] = {u, v, nrm, bitcast(lab)};  pos[t] = {px, py};  z_s[t] = z
// Launched with extra blocks: t >= NBATCH*P threads only serve the grid-
// strided zero/table loops (3x faster hough zeroing).
__global__ void prep_kernel(const int* __restrict__ label,
                            const float* __restrict__ vp,
                            float4* __restrict__ packed,
                            float2* __restrict__ pos,
                            float* __restrict__ z_s,
                            int4* __restrict__ hough4,
                            float* __restrict__ tab) {
    int t = blockIdx.x * blockDim.x + threadIdx.x;
    const int nthreads = gridDim.x * blockDim.x;

    // zero the hough accumulator (ws is poisoned 0xAA before every launch)
    const int HTOT4 = NBATCH * NCLS * P / 4;    // 52800 int4
    for (int q = t; q < HTOT4; q += nthreads) hough4[q] = make_int4(0, 0, 0, 0);

    // dist+EPS lookup table over integer displacement (|a|<=79, |b|<=59).
    // d2 = 64*(a*a+b*b) < 2^24 is an exact f32 integer, so this is the exact
    // reference chain: sqrtf(d2) correctly rounded, then +EPS rounded.
    for (int q = t; q < TSIZE; q += nthreads) {
        int a = q / TSTRIDE, b = q % TSTRIDE;
        float d2f = (float)(64 * (a * a + b * b));
        tab[q] = sqrtf(d2f) + EPSF;
    }

    if (t >= NBATCH * P) return;
    int n = t / P, p = t % P;
    int hs = p / WS_, ws = p % WS_;
    int y = hs * 8, x = ws * 8;
    int lab = label[((size_t)n * H + y) * W + x];
    const size_t HW = (size_t)H * W;
    size_t base = ((size_t)n * (3 * NCLS) + 3 * lab) * HW + (size_t)y * W + x;
    float u = vp[base];
    float v = vp[base + HW];
    float z = vp[base + 2 * HW];
    float nrm = sqrtf(u * u + v * v) + EPSF;    // exact, same as reference
    packed[t] = make_float4(u, v, nrm, __int_as_float(lab));
    pos[t] = make_float2((float)x, (float)y);   // exact small ints
    z_s[t] = z;
}

// ---------------- kernel A2: counting-sort voters by label --------------------
// sorted[slot] = {8u, 8v, nrm, bitcast(lab<<16 | hs<<8 | ws)} grouped by label.
// 8u is an exact exponent shift, and fl((8u)*ax) == fl(u*(8ax)) (identical
// real products, correct rounding) -> vote math stays bit-exact while the
// inner loop drops the *8 on the displacement.
// Order within a class is nondeterministic (atomic cursors) — harmless: the
// only consumer sums integer votes, which is order-invariant. The original-
// order arrays (packed/pos/z_s) are untouched, so final_kernel's float sums
// keep their exact current bit patterns.
__global__ void __launch_bounds__(1024) sort_kernel(
        const float4* __restrict__ packed,
        float4* __restrict__ sorted) {
    int n = blockIdx.x;
    int tid = threadIdx.x;
    __shared__ int cnt[NCLS];
    __shared__ int cur[NCLS];
    if (tid < NCLS) cnt[tid] = 0;
    __syncthreads();
    for (int p = tid; p < P; p += 1024) {
        int lab = __float_as_int(packed[n * P + p].w);
        atomicAdd(&cnt[lab], 1);
    }
    __syncthreads();
    if (tid == 0) {
        int s = 0;
        for (int c = 0; c < NCLS; ++c) { cur[c] = s; s += cnt[c]; }
    }
    __syncthreads();
    for (int p = tid; p < P; p += 1024) {
        float4 d = packed[n * P + p];
        int lab = __float_as_int(d.w);
        int slot = atomicAdd(&cur[lab], 1);
        int hs = p / WS_, ws = p % WS_;
        sorted[n * P + slot] =
            make_float4(d.x * 8.0f, d.y * 8.0f, d.z,
                        __int_as_float((lab << 16) | (hs << 8) | ws));
    }
}

// ---------------- kernel B: vote over label-sorted voters ---------------------
// grid (JTILES, ICHUNKS, NBATCH), block 256. Thread owns center j; loops over
// an i-chunk staged in LDS. Labels are piecewise-constant and wave-uniform, so
// the per-class count lives in one register and flushes with a rare uniform-
// branch atomic. No divide, no sqrt, no LDS histogram.
// Half-plane wave-skip: vote requires num >= MID*den > 0, so if no lane in
// the wave has num > 0 the whole tail (table read + f64 compare) is skipped
// via a uniform branch (~40% of iterations for random geometry).
// ILEN=192 amortizes the per-block table staging / sync / flush cost over 2x
// the work vs ILEN=96; 950 blocks (3.7 waves/SIMD) still hide latency.
__global__ void __launch_bounds__(256) vote_kernel(
        const float4* __restrict__ sorted,
        const float* __restrict__ tab,
        int* __restrict__ hough) {
    __shared__ float4 sdat[ILEN];
    __shared__ float stab[TSIZE];
    int tid = threadIdx.x;
    int j = blockIdx.x * 256 + tid;           // may be >= P in last tile
    int n = blockIdx.z;
    int i0 = blockIdx.y * ILEN;

    for (int q = tid; q < TSIZE; q += 256) stab[q] = tab[q];
    if (tid < ILEN) sdat[tid] = sorted[n * P + i0 + tid];
    __syncthreads();

    bool jok = j < P;
    int jc = jok ? j : 0;
    int jx = jc % WS_;
    int jy = jc / WS_;
    int* hrow = &hough[(size_t)n * NCLS * P + jc];  // + c*P per class

    int acc = 0;
    int prevlab = -1;
    for (int ii = 0; ii < ILEN; ++ii) {
        float4 d = sdat[ii];
        int meta = __float_as_int(d.w);
        int lab = meta >> 16;
        if (lab != prevlab) {                 // uniform branch (sorted labels)
            if (prevlab > 0 && acc && jok) atomicAdd(hrow + prevlab * P, acc);
            acc = 0;
            prevlab = lab;
        }
        if (lab == 0) continue;               // uniform branch
        int ix = meta & 0xFF;
        int iy = (meta >> 8) & 0xFF;
        int ax = jx - ix;
        int ay = jy - iy;
        float axf = (float)ax;                // exact small ints
        float ayf = (float)ay;
        float num = d.x * axf + d.y * ayf;    // == u*dx + v*dy bit-exact
        // num <= 0 can never vote (den > 0 always: nrm >= eps, t >= eps,
        // product >= 1e-16 >> FLT_MIN). ax==ay==0 gives num==0 -> false,
        // matching the reference's dist>0 gate.
        if (__any(num > 0.0f)) {
            float t = stab[abs(ax) * TSTRIDE + abs(ay)];   // dist+EPS, exact
            float den = d.z * t;              // nrm*(dist+EPS), exact ref chain
            // round(num/den) >= 0.9f <=> (double)num >= MID*(double)den
            acc += ((double)num >= MID * (double)den) ? 1 : 0;
        }
    }
    if (prevlab > 0 && acc && jok) atomicAdd(hrow + prevlab * P, acc);
}

// ---------------- kernel C: argmax + counts / inliers / z-mean / epilogue ------
__global__ void __launch_bounds__(256) final_kernel(
        const int* __restrict__ hough,
        const float4* __restrict__ packed,
        const float2* __restrict__ pos,
        const float* __restrict__ z_s,
        const float* __restrict__ extents,
        const float* __restrict__ meta,
        float* __restrict__ out) {
    int row_id = blockIdx.x;                  // n*NCLS + c
    int n = row_id / NCLS, c = row_id % NCLS;
    int tid = threadIdx.x;                    // 256

    // --- phase 1: argmax over j (first-max tie-break, matches jnp.argmax) ---
    const int* row = &hough[(size_t)row_id * P];
    int bi = tid;
    int bv = row[bi];
    for (int jj = tid + 256; jj < P; jj += 256) {
        int v = row[jj];
        if (v > bv) { bv = v; bi = jj; }      // keeps smallest index per stride
    }
    __shared__ int sv[256], si[256];
    sv[tid] = bv; si[tid] = bi;
    __syncthreads();
    for (int s = 128; s > 0; s >>= 1) {
        if (tid < s) {
            int v2 = sv[tid + s], i2 = si[tid + s];
            if (v2 > sv[tid] || (v2 == sv[tid] && i2 < si[tid])) {
                sv[tid] = v2; si[tid] = i2;
            }
        }
        __syncthreads();
    }
    int b = si[0];
    float mv = (float)sv[0];
    __syncthreads();

    // --- phase 2: counts, inliers at best, z sum ---
    // NOTE: iteration order (i = tid, tid+256, ... then tree reduce) is what
    // currently reproduces the reference float sums bit-exactly — do not
    // change the mapping or order.
    float pxb = (float)((b % WS_) * 8);
    float pyb = (float)((b / WS_) * 8);
    int cnt = 0, nin = 0;
    float zs = 0.0f;
    for (int i = tid; i < P; i += 256) {
        float4 d = packed[n * P + i];
        int lab = __float_as_int(d.w);
        if (lab != c) continue;
        cnt++;
        if (c == 0) continue;                 // fg condition kills votes anyway
        float2 pp = pos[n * P + i];
        float dx = pxb - pp.x;
        float dy = pyb - pp.y;
        float d2 = dx * dx + dy * dy;
        float dist = sqrtf(d2);
        float num = d.x * dx + d.y * dy;
        float den = d.z * (dist + EPSF);
        float cosang = num / den;
        if ((cosang >= 0.9f) && (d2 > 0.0f)) {
            nin++;
            zs += z_s[n * P + i];
        }
    }
    __shared__ int sc[256], sn[256];
    __shared__ float sz[256];
    sc[tid] = cnt; sn[tid] = nin; sz[tid] = zs;
    __syncthreads();
    for (int s = 128; s > 0; s >>= 1) {
        if (tid < s) {
            sc[tid] += sc[tid + s];
            sn[tid] += sn[tid + s];
            sz[tid] += sz[tid + s];
        }
        __syncthreads();
    }
    if (tid == 0) {
        float cntf = (float)sc[0];
        float ninf = (float)sn[0];
        float z_mean = sz[0] / fmaxf(ninf, 1.0f);
        float zc = fmaxf(z_mean, 0.001f);
        bool valid = (cntf * 64.0f >= 500.0f) && (mv >= 10.0f)
                     && (mv >= 0.02f * cntf) && (c > 0);
        float vm = valid ? 1.0f : 0.0f;
        float fx  = meta[n * 9 + 0];
        float ppx = meta[n * 9 + 2];
        float fy  = meta[n * 9 + 4];
        float ppy = meta[n * 9 + 5];
        float ex = extents[c * 3 + 0];
        float ey = extents[c * 3 + 1];
        float bw = ex * fx / zc;
        float bh = ey * fy / zc;
        float cx = pxb, cy = pyb;
        float tx = (cx - ppx) * zc / fx;
        float ty = (cy - ppy) * zc / fy;
        float* box = out + (size_t)row_id * 7;
        box[0] = (float)n * vm;
        box[1] = (float)c * vm;
        box[2] = (cx - bw / 2.0f) * vm;
        box[3] = (cy - bh / 2.0f) * vm;
        box[4] = (cx + bw / 2.0f) * vm;
        box[5] = (cy + bh / 2.0f) * vm;
        box[6] = mv * vm;
        float* pose = out + (size_t)NBATCH * NCLS * 7 + (size_t)row_id * 7;
        pose[0] = vm;
        pose[1] = 0.0f;
        pose[2] = 0.0f;
        pose[3] = 0.0f;
        pose[4] = tx * vm;
        pose[5] = ty * vm;
        pose[6] = zc * vm;
    }
}

extern "C" void kernel_launch(void* const* d_in, const int* in_sizes, int n_in,
                              void* d_out, int out_size, void* d_ws, size_t ws_size,
                              hipStream_t stream) {
    const int*   label   = (const int*)d_in[0];     // (N,H,W) int32
    const float* vp      = (const float*)d_in[1];   // (N,66,H,W) f32
    const float* extents = (const float*)d_in[2];   // (22,3) f32
    // d_in[3] = poses (unused)
    const float* meta    = (const float*)d_in[4];   // (N,9) f32
    float* out = (float*)d_out;                     // 616 f32

    char* ws = (char*)d_ws;
    // layout (bytes): packed[9600]f4 (153600) | pos[9600]f2 (76800) |
    //   z_s[9600]f32 (38400) | hough[2*22*4800]i32 (844800) |
    //   sorted[9600]f4 (153600) | tab[4880]f32 (19520)
    float4* packed = (float4*)(ws + 0);
    float2* pos    = (float2*)(ws + 153600);
    float*  z_s    = (float*)(ws + 153600 + 76800);
    int*    hough  = (int*)(ws + 153600 + 76800 + 38400);
    float4* sorted = (float4*)(ws + 153600 + 76800 + 38400 + 844800);
    float*  tab    = (float*)(ws + 153600 + 76800 + 38400 + 844800 + 153600);

    // 128 blocks: extra blocks speed up the grid-strided hough zero + table.
    prep_kernel<<<128, 256, 0, stream>>>(
        label, vp, packed, pos, z_s, (int4*)hough, tab);

    sort_kernel<<<NBATCH, 1024, 0, stream>>>(packed, sorted);

    dim3 vgrid(JTILES, ICHUNKS, NBATCH);
    vote_kernel<<<vgrid, 256, 0, stream>>>(sorted, tab, hough);

    final_kernel<<<NBATCH * NCLS, 256, 0, stream>>>(hough, packed, pos, z_s,
                                                    extents, meta, out);
}